// Round 5
// baseline (264.262 us; speedup 1.0000x reference)
//
#include <hip/hip_runtime.h>
#include <stdint.h>

// Problem constants (N,C,H,W fixed by the reference)
#define NB 32
#define CH 256
#define HH 56
#define WW 56
#define HWSZ (HH*WW)            // 3136
#define NPIX (NB*HWSZ)          // 100352
#define HP 58
#define WP 58
#define PADPIX (NB*HP*WP)       // 107648
#define NTAPS 9
#define KKE (CH*NTAPS)          // 2304
#define NPIXD 100352.0
#define WQ_CONV (NTAPS*8*8*64*16)   // 589824 bytes of prepacked weights per conv
#define HSTRIDE 272             // halo row stride (non-mult-of-128 -> conflict-free)

typedef int int4v  __attribute__((ext_vector_type(4)));
typedef int int16v __attribute__((ext_vector_type(16)));

// ---------------- init: zero stats accumulators (8-way split) ----------------
__global__ void init_kernel(long long* __restrict__ sums8) {
    int t = blockIdx.x*256 + threadIdx.x;
    if (t < 2*8*512) sums8[t] = 0;     // 2 convs x 8 splits x 256 ch x {sum,sumsq}
}

// ---------------- prepack weights into MFMA B-fragment layout ----------------
// wq[conv][tap][ks][nb][lane][16B]: byte b of lane l = sign(w[o][cin][tap])
// with o = nb*32 + (l&31), cin = ks*32 + (l>>5)*16 + b.
__global__ void wqpack_kernel(const float* __restrict__ w1, const float* __restrict__ w2,
                              int8_t* __restrict__ wq) {
    int t = blockIdx.x*256 + threadIdx.x;     // 144 blocks -> 36864 threads
    int conv = blockIdx.y;
    const float* w = conv ? w2 : w1;
    int lane = t & 63;
    int g = t >> 6;                 // (tap*8+ks)*8+nb
    int nb = g & 7, h = g >> 3;
    int ks = h & 7, tap = h >> 3;
    int o = nb*32 + (lane & 31);
    int cin0 = ks*32 + (lane >> 5)*16;
    int wd[4];
    #pragma unroll
    for (int q = 0; q < 4; ++q) {
        int wv = 0;
        #pragma unroll
        for (int j = 0; j < 4; ++j) {
            float v = w[(size_t)(o*CH + cin0 + q*4 + j)*NTAPS + tap];
            int s = (v > 0.f) ? 1 : ((v < 0.f) ? -1 : 0);
            wv |= (s & 0xff) << (8*j);
        }
        wd[q] = wv;
    }
    *(int4v*)(wq + (size_t)conv*WQ_CONV + (size_t)t*16) = (int4v){wd[0], wd[1], wd[2], wd[3]};
}

// ---------------- alpha[o] = mean |w| over (I,3,3) ----------------
__global__ void alpha_kernel(const float* __restrict__ w1, const float* __restrict__ w2,
                             float* __restrict__ alpha) {
    int o = blockIdx.x; int conv = blockIdx.y;
    const float* w = conv ? w2 : w1;
    float s = 0.f;
    for (int i = threadIdx.x; i < KKE; i += 256) s += fabsf(w[(size_t)o*KKE + i]);
    for (int off = 32; off; off >>= 1) s += __shfl_down(s, off);
    __shared__ float l[4];
    int lane = threadIdx.x & 63, wv = threadIdx.x >> 6;
    if (lane == 0) l[wv] = s;
    __syncthreads();
    if (threadIdx.x == 0) alpha[conv*CH + o] = (l[0]+l[1]+l[2]+l[3]) * (1.f/KKE);
}

// ---------------- pack activations: x -> int8 sign, padded, ch-contiguous ----------------
__global__ void pack_x_kernel(const float* __restrict__ x, int8_t* __restrict__ apad) {
    int p = blockIdx.x*256 + threadIdx.x;
    if (p >= PADPIX) return;
    int n  = p / (HP*WP);
    int r  = p - n*(HP*WP);
    int hp = r / WP, wp = r - hp*WP;
    int4v* dst = (int4v*)(apad + (size_t)p*CH);
    if (hp >= 1 && hp <= HH && wp >= 1 && wp <= WW) {
        const float* xb = x + (size_t)n*CH*HWSZ + (hp-1)*WW + (wp-1);
        #pragma unroll 2
        for (int c16 = 0; c16 < 16; ++c16) {
            int wd[4];
            #pragma unroll
            for (int q = 0; q < 4; ++q) {
                int wv = 0;
                #pragma unroll
                for (int j = 0; j < 4; ++j) {
                    float v = xb[(size_t)(c16*16 + q*4 + j)*HWSZ];
                    int s = (v > 0.f) ? 1 : ((v < 0.f) ? -1 : 0);
                    wv |= (s & 0xff) << (8*j);
                }
                wd[q] = wv;
            }
            dst[c16] = (int4v){wd[0], wd[1], wd[2], wd[3]};
        }
    } else {
        int4v z = {0,0,0,0};
        #pragma unroll
        for (int c16 = 0; c16 < 16; ++c16) dst[c16] = z;
    }
}

// ---------------- pack sign(BN1(cnt)) -> int8, padded ----------------
__global__ void pack_s_kernel(const int16_t* __restrict__ cnt,
                              const float* __restrict__ ab,   // a=ab[0..255], b=ab[256..511]
                              int8_t* __restrict__ apad) {
    int p = blockIdx.x*256 + threadIdx.x;
    if (p >= PADPIX) return;
    int n  = p / (HP*WP);
    int r  = p - n*(HP*WP);
    int hp = r / WP, wp = r - hp*WP;
    int4v* dst = (int4v*)(apad + (size_t)p*CH);
    if (hp >= 1 && hp <= HH && wp >= 1 && wp <= WW) {
        const int4v* cb = (const int4v*)(cnt + ((size_t)n*HWSZ + (hp-1)*WW + (wp-1))*CH);
        #pragma unroll 2
        for (int c16 = 0; c16 < 16; ++c16) {
            int4v u0 = cb[c16*2], u1 = cb[c16*2+1];
            int wd[4];
            #pragma unroll
            for (int q = 0; q < 4; ++q) {
                int wv = 0;
                #pragma unroll
                for (int j = 0; j < 4; ++j) {
                    int e = q*4 + j;                       // 0..15 within this 16-ch group
                    int word = (e < 8) ? u0[e >> 1] : u1[(e-8) >> 1];
                    int sval = (e & 1) ? (word >> 16) : ((word << 16) >> 16);
                    int ch = c16*16 + e;
                    float v = fmaf(ab[ch], (float)sval, ab[CH + ch]);
                    int s = (v > 0.f) ? 1 : ((v < 0.f) ? -1 : 0);
                    wv |= (s & 0xff) << (8*j);
                }
                wd[q] = wv;
            }
            dst[c16] = (int4v){wd[0], wd[1], wd[2], wd[3]};
        }
    } else {
        int4v z = {0,0,0,0};
        #pragma unroll
        for (int c16 = 0; c16 < 16; ++c16) dst[c16] = z;
    }
}

// ---------------- int8 MFMA implicit-GEMM 3x3 conv, fused stats ----------------
// wg = {2 images} x 8x8 pixels x 256 outs.  M=128, N=256, K=2304, fully unrolled K.
// Ring-buffer prefetch: A (LDS) 2 iters ahead, B (global/L2) 4 iters ahead.
#define AOFF(IT) (((((IT)>>3)/3)*10 + (((IT)>>3)%3))*HSTRIDE + ((IT)&7)*32)

__global__ __launch_bounds__(256, 2) void conv_kernel(
        const int8_t* __restrict__ apad, const int8_t* __restrict__ wq,
        int16_t* __restrict__ cnt, long long* __restrict__ sums8) {
    __shared__ __attribute__((aligned(16))) int8_t halo[200*HSTRIDE];   // 54.4 KB
    int b = blockIdx.x;                           // 784 = 16 image-pairs x 49 tiles
    int tile = b % 49, npair = b / 49;
    int ty = tile / 7, tx = tile % 7;
    int n0 = npair * 2;
    int t = threadIdx.x;

    // stage halo: 200 pixels x 16 chunks of 16B; row stride 272 -> conflict-free
    #pragma unroll 1
    for (int j = 0; j < 13; ++j) {
        int idx = t + j*256;
        if (idx < 3200) {
            int pix = idx >> 4, c16 = idx & 15;
            int img = (pix >= 100) ? 1 : 0;
            int hp = pix - img*100;
            int dr = hp / 10, dc = hp - dr*10;
            const int4v* src = (const int4v*)(apad +
                ((size_t)(((n0+img)*HP + ty*8+dr)*WP + tx*8+dc))*CH + c16*16);
            *(int4v*)&halo[pix*HSTRIDE + c16*16] = *src;
        }
    }
    __syncthreads();

    int lane = t & 63;
    int wv = __builtin_amdgcn_readfirstlane(t >> 6);   // wave-uniform -> SGPR addressing
    int kh = lane >> 5, lr = lane & 31;
    int r0 = lr >> 3, c0 = lr & 7;
    int base0 = (r0*10 + c0)*HSTRIDE + kh*16;     // img0, rows 0..3
    int base1 = base0 + 40*HSTRIDE;               // img0, rows 4..7
    int base2 = base0 + 100*HSTRIDE;              // img1
    int base3 = base0 + 140*HSTRIDE;

    const int8_t* wp0 = wq + wv*2048 + lane*16;
    const int8_t* wp1 = wp0 + 1024;

    int16v acc00, acc01, acc10, acc11, acc20, acc21, acc30, acc31;
    #pragma unroll
    for (int i = 0; i < 16; ++i) {
        acc00[i]=0; acc01[i]=0; acc10[i]=0; acc11[i]=0;
        acc20[i]=0; acc21[i]=0; acc30[i]=0; acc31[i]=0;
    }

    // prefetch rings: A depth-2 (3 slots), B depth-4 (5 slots); all indices
    // compile-time constants under full unroll -> pure registers.
    int4v ar0[3], ar1[3], ar2[3], ar3[3];
    int4v br0[5], br1[5];

    #pragma unroll
    for (int pf = 0; pf < 2; ++pf) {
        ar0[pf] = *(const int4v*)&halo[base0 + AOFF(pf)];
        ar1[pf] = *(const int4v*)&halo[base1 + AOFF(pf)];
        ar2[pf] = *(const int4v*)&halo[base2 + AOFF(pf)];
        ar3[pf] = *(const int4v*)&halo[base3 + AOFF(pf)];
    }
    #pragma unroll
    for (int pf = 0; pf < 4; ++pf) {
        br0[pf] = *(const int4v*)(wp0 + pf*8192);
        br1[pf] = *(const int4v*)(wp1 + pf*8192);
    }

    #pragma unroll
    for (int it = 0; it < 72; ++it) {             // 9 taps x 8 k-steps, FULL unroll
        if (it + 4 < 72) {                        // B: 4 iters ahead (~292 cyc >= L2 lat)
            br0[(it+4)%5] = *(const int4v*)(wp0 + (it+4)*8192);
            br1[(it+4)%5] = *(const int4v*)(wp1 + (it+4)*8192);
        }
        if (it + 2 < 72) {                        // A: 2 iters ahead (~146 cyc >= LDS lat)
            ar0[(it+2)%3] = *(const int4v*)&halo[base0 + AOFF(it+2)];
            ar1[(it+2)%3] = *(const int4v*)&halo[base1 + AOFF(it+2)];
            ar2[(it+2)%3] = *(const int4v*)&halo[base2 + AOFF(it+2)];
            ar3[(it+2)%3] = *(const int4v*)&halo[base3 + AOFF(it+2)];
        }
        int4v a0 = ar0[it%3], a1 = ar1[it%3], a2 = ar2[it%3], a3 = ar3[it%3];
        int4v b0 = br0[it%5], b1 = br1[it%5];
        acc00 = __builtin_amdgcn_mfma_i32_32x32x32_i8(a0, b0, acc00, 0,0,0);
        acc01 = __builtin_amdgcn_mfma_i32_32x32x32_i8(a0, b1, acc01, 0,0,0);
        acc10 = __builtin_amdgcn_mfma_i32_32x32x32_i8(a1, b0, acc10, 0,0,0);
        acc11 = __builtin_amdgcn_mfma_i32_32x32x32_i8(a1, b1, acc11, 0,0,0);
        acc20 = __builtin_amdgcn_mfma_i32_32x32x32_i8(a2, b0, acc20, 0,0,0);
        acc21 = __builtin_amdgcn_mfma_i32_32x32x32_i8(a2, b1, acc21, 0,0,0);
        acc30 = __builtin_amdgcn_mfma_i32_32x32x32_i8(a3, b0, acc30, 0,0,0);
        acc31 = __builtin_amdgcn_mfma_i32_32x32x32_i8(a3, b1, acc31, 0,0,0);
    }

    // epilogue: C layout col=lane&31, row=(reg&3)+8*(reg>>2)+4*(lane>>5)
#define STOREACC(ACC, M, J) do { \
        int ch_ = (wv*2 + (J))*32 + lr; \
        int img_ = (M) >> 1; \
        _Pragma("unroll") \
        for (int reg = 0; reg < 16; ++reg) { \
            int row_ = (reg & 3) + 8*(reg >> 2) + 4*kh; \
            int pm_ = ((M) & 1)*32 + row_; \
            int rr_ = pm_ >> 3, cc_ = pm_ & 7; \
            cnt[(size_t)(((n0+img_)*HH + ty*8 + rr_)*WW + tx*8 + cc_)*CH + ch_] = (int16_t)ACC[reg]; \
        } \
    } while (0)

    STOREACC(acc00, 0, 0); STOREACC(acc01, 0, 1);
    STOREACC(acc10, 1, 0); STOREACC(acc11, 1, 1);
    STOREACC(acc20, 2, 0); STOREACC(acc21, 2, 1);
    STOREACC(acc30, 3, 0); STOREACC(acc31, 3, 1);
#undef STOREACC

    // fused per-channel stats: sum / sumsq over this block's 128 pixels
    int s1a = 0, s2a = 0, s1b = 0, s2b = 0;
    #pragma unroll
    for (int reg = 0; reg < 16; ++reg) {
        int v;
        v = acc00[reg]; s1a += v; s2a += v*v;
        v = acc10[reg]; s1a += v; s2a += v*v;
        v = acc20[reg]; s1a += v; s2a += v*v;
        v = acc30[reg]; s1a += v; s2a += v*v;
        v = acc01[reg]; s1b += v; s2b += v*v;
        v = acc11[reg]; s1b += v; s2b += v*v;
        v = acc21[reg]; s1b += v; s2b += v*v;
        v = acc31[reg]; s1b += v; s2b += v*v;
    }
    s1a += __shfl_down(s1a, 32); s2a += __shfl_down(s2a, 32);
    s1b += __shfl_down(s1b, 32); s2b += __shfl_down(s2b, 32);
    if (lane < 32) {
        long long* sp = sums8 + (size_t)(b & 7)*512;
        int ch0 = wv*64 + lr, ch1 = ch0 + 32;
        atomicAdd((unsigned long long*)&sp[2*ch0],   (unsigned long long)(long long)s1a);
        atomicAdd((unsigned long long*)&sp[2*ch0+1], (unsigned long long)(long long)s2a);
        atomicAdd((unsigned long long*)&sp[2*ch1],   (unsigned long long)(long long)s1b);
        atomicAdd((unsigned long long*)&sp[2*ch1+1], (unsigned long long)(long long)s2b);
    }
}

// ---------------- BN coefficients: BN(alpha*cnt) = a*cnt + b ----------------
__global__ void bncoef_kernel(const long long* __restrict__ sums8,
                              const float* __restrict__ alpha,
                              const float* __restrict__ gamma, const float* __restrict__ beta,
                              float* __restrict__ ab) {
    int o = threadIdx.x;
    long long S1i = 0, S2i = 0;
    #pragma unroll
    for (int k = 0; k < 8; ++k) {
        S1i += sums8[(size_t)k*512 + 2*o];
        S2i += sums8[(size_t)k*512 + 2*o + 1];
    }
    double S1 = (double)S1i, S2 = (double)S2i;
    double mean = S1 / NPIXD;
    double var  = S2 / NPIXD - mean*mean;
    double al   = (double)alpha[o];
    double rs   = 1.0 / sqrt(al*al*var + 1e-5);
    double a    = (double)gamma[o] * al * rs;
    ab[o]      = (float)a;
    ab[CH + o] = (float)((double)beta[o] - a*mean);
}

// ---------------- fused epilogue: out = a2*cnt2 + b2 + x  (LDS transpose) ----------------
__global__ __launch_bounds__(256) void final_kernel(const int16_t* __restrict__ cnt,
        const float* __restrict__ x, const float* __restrict__ ab, float* __restrict__ out) {
    __shared__ int4v lsd4[64*32];                 // 64 pixels x 512B, swizzled
    int8_t* lb = (int8_t*)lsd4;
    int b = blockIdx.x;                           // 1568 = 32 n x 49 tiles
    int n = b / 49, tile = b - n*49;
    int p0 = tile * 64;
    int t = threadIdx.x;
    const int4v* src = (const int4v*)(cnt + ((size_t)n*HWSZ + p0)*CH);
    #pragma unroll
    for (int j = 0; j < 8; ++j) {
        int c = t + j*256;                        // 2048 16B-chunks
        int pix = c >> 5, c16 = c & 31;
        *(int4v*)&lb[pix*512 + ((c16*16) ^ ((pix & 15) << 4))] = src[c];
    }
    __syncthreads();
    int pixL = t & 63;
    int cb = (t >> 6) * 64;
    #pragma unroll 1
    for (int i = 0; i < 8; ++i) {
        int ch0 = cb + i*8;
        int4v v = *(const int4v*)&lb[pixL*512 + ((ch0*2) ^ ((pixL & 15) << 4))];
        #pragma unroll
        for (int j = 0; j < 8; ++j) {
            int ch = ch0 + j;
            int word = v[j >> 1];
            int sval = (j & 1) ? (word >> 16) : ((word << 16) >> 16);
            size_t g = (size_t)(n*CH + ch)*HWSZ + p0 + pixL;
            out[g] = fmaf(ab[ch], (float)sval, ab[CH + ch]) + x[g];
        }
    }
}

extern "C" void kernel_launch(void* const* d_in, const int* in_sizes, int n_in,
                              void* d_out, int out_size, void* d_ws, size_t ws_size,
                              hipStream_t stream) {
    const float* x  = (const float*)d_in[0];
    const float* w1 = (const float*)d_in[1];
    const float* g1 = (const float*)d_in[2];
    const float* b1 = (const float*)d_in[3];
    const float* w2 = (const float*)d_in[4];
    const float* g2 = (const float*)d_in[5];
    const float* b2 = (const float*)d_in[6];
    float* out = (float*)d_out;

    char* ws = (char*)d_ws;
    size_t off = 0;
    auto alloc = [&](size_t nbytes) { char* pp = ws + off; off = (off + nbytes + 255) & ~(size_t)255; return pp; };
    int8_t*   apad  = (int8_t*)alloc((size_t)PADPIX*CH);           // 27.6 MB
    int16_t*  cnt   = (int16_t*)alloc((size_t)NPIX*CH*2);          // 51.4 MB
    int8_t*   wq    = (int8_t*)alloc((size_t)2*WQ_CONV);           // 1.2 MB
    float*    alpha = (float*)alloc((size_t)2*CH*4);
    long long* sums8 = (long long*)alloc((size_t)2*8*512*8);       // 64 KB
    float*    ab    = (float*)alloc((size_t)2*2*CH*4);             // [a1,b1 | a2,b2]

    init_kernel<<<32, 256, 0, stream>>>(sums8);
    wqpack_kernel<<<dim3(144, 2), 256, 0, stream>>>(w1, w2, wq);
    alpha_kernel<<<dim3(CH, 2), 256, 0, stream>>>(w1, w2, alpha);
    pack_x_kernel<<<(PADPIX + 255)/256, 256, 0, stream>>>(x, apad);

    conv_kernel<<<784, 256, 0, stream>>>(apad, wq, cnt, sums8);
    bncoef_kernel<<<1, CH, 0, stream>>>(sums8, alpha, g1, b1, ab);

    pack_s_kernel<<<(PADPIX + 255)/256, 256, 0, stream>>>(cnt, ab, apad);
    conv_kernel<<<784, 256, 0, stream>>>(apad, wq + WQ_CONV, cnt, sums8 + 8*512);
    bncoef_kernel<<<1, CH, 0, stream>>>(sums8 + 8*512, alpha + CH, g2, b2, ab + 2*CH);

    final_kernel<<<1568, 256, 0, stream>>>(cnt, x, ab + 2*CH, out);
}